// Round 1
// baseline (553.330 us; speedup 1.0000x reference)
//
#include <hip/hip_runtime.h>
#include <math.h>

// DeBERTa disentangled self-attention, fused (MI355X / gfx950).
// B=2, S=2048, D=64, H=12, K_SPAN=512.
// score[i,j] = (q_i.k_j + q_i.pk[c] + k_j.pq[c]) / sqrt(192),  c = clip(i-j+512, 0, 1023)
// kernel 1: fp32 projections -> bf16 q/k/vT/pk/pq in ws (22MB).
// kernel 2: flash-style fused attention, MFMA 16x16x32 bf16, position terms via
//           sliding diagonal-band MFMAs gathered through LDS tables.

#define S_LEN 2048
#define NH    12
#define NBH   24
#define TWOK  1024
#define NJT   32
#define QSZ   3145728   // NBH * S_LEN * 64
#define PSZ   786432    // NH * TWOK * 64

typedef __bf16 bf16x8 __attribute__((ext_vector_type(8)));
typedef unsigned short u16x8 __attribute__((ext_vector_type(8)));
typedef float f32x4 __attribute__((ext_vector_type(4)));

__device__ __forceinline__ unsigned short f2bf(float f) {
  unsigned u = __builtin_bit_cast(unsigned, f);
  u += 0x7FFFu + ((u >> 16) & 1u);            // RNE
  return (unsigned short)(u >> 16);
}
__device__ __forceinline__ float bf2f(unsigned short h) {
  return __builtin_bit_cast(float, ((unsigned)h) << 16);
}

// ---------------------------------------------------------------- projections
__global__ __launch_bounds__(256) void proj_kernel(
    const float* __restrict__ Hx, const float* __restrict__ pos,
    const float* __restrict__ Wq, const float* __restrict__ bq,
    const float* __restrict__ Wk, const float* __restrict__ bk,
    const float* __restrict__ Wv, const float* __restrict__ bv,
    const float* __restrict__ Wpq, const float* __restrict__ bpq,
    const float* __restrict__ Wpk, const float* __restrict__ bpk,
    unsigned short* __restrict__ ws) {
  unsigned short* qg  = ws;
  unsigned short* kg  = ws + QSZ;
  unsigned short* vtg = ws + 2 * QSZ;
  unsigned short* pkg = ws + 3 * QSZ;
  unsigned short* pqg = ws + 3 * QSZ + PSZ;

  __shared__ float hs[8][64];
  int bid = blockIdx.x, tid = threadIdx.x;

  if (bid < 512) {                       // q/k/v rows: 8 sequence rows per block
    int gr0 = bid * 8;                   // global row in [0, 4096)
    for (int idx = tid; idx < 512; idx += 256)
      hs[idx >> 6][idx & 63] = Hx[gr0 * 64 + idx];
    __syncthreads();
    for (int o = tid; o < 2304; o += 256) {
      int mat = o / 768, oh = o - mat * 768;
      const float* W = (mat == 0 ? Wq : (mat == 1 ? Wk : Wv)) + oh * 64;
      float bias = (mat == 0 ? bq : (mat == 1 ? bk : bv))[oh];
      float acc[8];
      #pragma unroll
      for (int rr = 0; rr < 8; ++rr) acc[rr] = bias;
      #pragma unroll
      for (int dd = 0; dd < 64; dd += 4) {
        float4 w4 = *(const float4*)(W + dd);
        #pragma unroll
        for (int rr = 0; rr < 8; ++rr)
          acc[rr] += hs[rr][dd] * w4.x + hs[rr][dd + 1] * w4.y +
                     hs[rr][dd + 2] * w4.z + hs[rr][dd + 3] * w4.w;
      }
      int h = oh >> 6, d = oh & 63;
      #pragma unroll
      for (int rr = 0; rr < 8; ++rr) {
        int gr = gr0 + rr, b = gr >> 11, i = gr & 2047, bh = b * NH + h;
        unsigned short v = f2bf(acc[rr]);
        if (mat == 0)      qg[(bh * S_LEN + i) * 64 + d] = v;
        else if (mat == 1) kg[(bh * S_LEN + i) * 64 + d] = v;
        else               vtg[(bh * 64 + d) * S_LEN + i] = v;   // V transposed
      }
    }
  } else {                               // pos rows: pk (Wpk) and pq (Wpq)
    int r0 = (bid - 512) * 8;            // pos row in [0, 1024)
    for (int idx = tid; idx < 512; idx += 256)
      hs[idx >> 6][idx & 63] = pos[r0 * 64 + idx];
    __syncthreads();
    for (int o = tid; o < 1536; o += 256) {
      int mat = o / 768, oh = o - mat * 768;
      const float* W = (mat == 0 ? Wpk : Wpq) + oh * 64;
      float bias = (mat == 0 ? bpk : bpq)[oh];
      float acc[8];
      #pragma unroll
      for (int rr = 0; rr < 8; ++rr) acc[rr] = bias;
      #pragma unroll
      for (int dd = 0; dd < 64; dd += 4) {
        float4 w4 = *(const float4*)(W + dd);
        #pragma unroll
        for (int rr = 0; rr < 8; ++rr)
          acc[rr] += hs[rr][dd] * w4.x + hs[rr][dd + 1] * w4.y +
                     hs[rr][dd + 2] * w4.z + hs[rr][dd + 3] * w4.w;
      }
      int h = oh >> 6, d = oh & 63;
      #pragma unroll
      for (int rr = 0; rr < 8; ++rr) {
        int r = r0 + rr;
        unsigned short v = f2bf(acc[rr]);
        if (mat == 0) pkg[(h * TWOK + r) * 64 + d] = v;
        else          pqg[(h * TWOK + r) * 64 + d] = v;
      }
    }
  }
}

// ---------------------------------------------------------------- fused attention
// block = 256 thr (4 waves); block -> (bh, itile of 64 q-rows); wave -> 16 q-rows.
// LDS (73KB): K tile + pk band + pq band (XOR-swizzled, ds_read_b128-clean),
// c2p table [4][16][132], p2c table transposed [128][66] (pads kill gather conflicts),
// P (64x64 bf16) overlaid on pk-tile rows 0..63 (safe: all pk reads end at B3).
__global__ __launch_bounds__(256, 2) void attn_kernel(
    const unsigned short* __restrict__ ws, float* __restrict__ out) {
  const unsigned short* qg  = ws;
  const unsigned short* kg  = ws + QSZ;
  const unsigned short* vtg = ws + 2 * QSZ;
  const unsigned short* pkg = ws + 3 * QSZ;
  const unsigned short* pqg = ws + 3 * QSZ + PSZ;

  __shared__ __align__(16) unsigned short k_t[64 * 64];
  __shared__ __align__(16) unsigned short pk_t[128 * 64];
  __shared__ __align__(16) unsigned short pq_t[128 * 64];
  __shared__ __align__(16) unsigned short c2p_t[4 * 16 * 132];
  __shared__ __align__(16) unsigned short p2c_t[128 * 66];

  int bid = blockIdx.x;
  int bh = bid >> 5, itile = bid & 31;
  int b = bh / NH, h = bh - b * NH;
  int tid = threadIdx.x;
  int w = tid >> 6, l = tid & 63;
  int lg = l >> 4, lr = l & 15;

  const unsigned short* qbase  = qg  + bh * (S_LEN * 64);
  const unsigned short* kbase  = kg  + bh * (S_LEN * 64);
  const unsigned short* vtbase = vtg + bh * (64 * S_LEN);
  const unsigned short* pkbase = pkg + h * (TWOK * 64);
  const unsigned short* pqbase = pqg + h * (TWOK * 64);

  const float CS = 1.4426950408889634f / sqrtf(192.0f);  // log2(e)/sqrt(3*64)

  // Q A-frags in registers: lane holds Q[i = lr][k = ks*32 + 8*lg + e]
  int irow = itile * 64 + w * 16 + lr;
  bf16x8 qf[2];
  #pragma unroll
  for (int ks = 0; ks < 2; ++ks)
    qf[ks] = __builtin_bit_cast(bf16x8,
        *(const u16x8*)(qbase + irow * 64 + ks * 32 + 8 * lg));

  f32x4 ctx[4];
  float m_[4], l_[4];
  #pragma unroll
  for (int r = 0; r < 4; ++r) { m_[r] = -1e30f; l_[r] = 0.f; }
  #pragma unroll
  for (int db = 0; db < 4; ++db) ctx[db] = (f32x4){0.f, 0.f, 0.f, 0.f};

  for (int jt = 0; jt < NJT; ++jt) {
    int j0 = jt * 64;
    int R0 = itile * 64 - j0 + 512;
    int relmin = R0 - 63; relmin = relmin < 0 ? 0 : (relmin > 1023 ? 1023 : relmin);
    int relmax = R0 + 63; relmax = relmax < 0 ? 0 : (relmax > 1023 ? 1023 : relmax);
    int bstart = relmin > 896 ? 896 : relmin;
    int nb_lo = (relmin - bstart) >> 4, nb_hi = (relmax - bstart) >> 4;
    int p_lo = nb_lo >> 1, p_hi = nb_hi >> 1;

    __syncthreads();   // B1: prior iteration's LDS consumers done

    // ---- stage K tile (always) + used slices of pk/pq band; swizzled writes
    {
      #pragma unroll
      for (int pass = 0; pass < 2; ++pass) {
        int o = tid * 16 + pass * 4096;
        int row = o >> 7, cb = (o & 127) >> 1;           // cb in ushorts
        u16x8 v = *(const u16x8*)(kbase + (j0 + row) * 64 + cb);
        *(u16x8*)(&k_t[row * 64 + (cb ^ ((row & 7) << 3))]) = v;
      }
      for (int pass = p_lo; pass <= p_hi; ++pass) {
        int o = tid * 16 + pass * 4096;
        int row = o >> 7, cb = (o & 127) >> 1;
        u16x8 v = *(const u16x8*)(pkbase + (bstart + row) * 64 + cb);
        *(u16x8*)(&pk_t[row * 64 + (cb ^ ((row & 7) << 3))]) = v;
        u16x8 v2 = *(const u16x8*)(pqbase + (bstart + row) * 64 + cb);
        *(u16x8*)(&pq_t[row * 64 + (cb ^ ((row & 7) << 3))]) = v2;
      }
    }
    __syncthreads();   // B2: tiles ready

    // ---- QK^T : s[jb] holds S[4*lg+r][jb*16+lr]
    f32x4 s[4];
    #pragma unroll
    for (int jb = 0; jb < 4; ++jb) {
      f32x4 acc = (f32x4){0.f, 0.f, 0.f, 0.f};
      #pragma unroll
      for (int ks = 0; ks < 2; ++ks) {
        int row = jb * 16 + lr, c0 = ks * 32 + 8 * lg;
        bf16x8 bfrag = __builtin_bit_cast(bf16x8,
            *(const u16x8*)(&k_t[row * 64 + (c0 ^ ((row & 7) << 3))]));
        acc = __builtin_amdgcn_mfma_f32_16x16x32_bf16(qf[ks], bfrag, acc, 0, 0, 0);
      }
      s[jb] = acc;
    }

    // ---- p2c A-frags: this wave's 16 k-rows
    bf16x8 af[2];
    #pragma unroll
    for (int ks = 0; ks < 2; ++ks) {
      int row = w * 16 + lr, c0 = ks * 32 + 8 * lg;
      af[ks] = __builtin_bit_cast(bf16x8,
          *(const u16x8*)(&k_t[row * 64 + (c0 ^ ((row & 7) << 3))]));
    }

    // ---- diagonal position bands -> LDS tables (only used nb blocks)
    for (int nb = nb_lo; nb <= nb_hi; ++nb) {
      f32x4 bc = (f32x4){0.f, 0.f, 0.f, 0.f};
      f32x4 bp = (f32x4){0.f, 0.f, 0.f, 0.f};
      #pragma unroll
      for (int ks = 0; ks < 2; ++ks) {
        int row = nb * 16 + lr, c0 = ks * 32 + 8 * lg;
        int sw = row * 64 + (c0 ^ ((row & 7) << 3));
        bf16x8 fk = __builtin_bit_cast(bf16x8, *(const u16x8*)(&pk_t[sw]));
        bf16x8 fq = __builtin_bit_cast(bf16x8, *(const u16x8*)(&pq_t[sw]));
        bc = __builtin_amdgcn_mfma_f32_16x16x32_bf16(qf[ks], fk, bc, 0, 0, 0);
        bp = __builtin_amdgcn_mfma_f32_16x16x32_bf16(af[ks], fq, bp, 0, 0, 0);
      }
      #pragma unroll
      for (int r = 0; r < 4; ++r) {
        c2p_t[w * 2112 + (4 * lg + r) * 132 + nb * 16 + lr] = f2bf(bc[r]);
        p2c_t[(nb * 16 + lr) * 66 + (w * 16 + 4 * lg + r)] = f2bf(bp[r]);
      }
    }
    __syncthreads();   // B3: tables ready (p2c is cross-wave)

    // ---- gather position terms, scale into exp2 domain
    #pragma unroll
    for (int jb = 0; jb < 4; ++jb) {
      #pragma unroll
      for (int r = 0; r < 4; ++r) {
        int i16 = 4 * lg + r;
        int ig = itile * 64 + w * 16 + i16;
        int jg = j0 + jb * 16 + lr;
        int rel = ig - jg + 512;
        rel = rel < 0 ? 0 : (rel > 1023 ? 1023 : rel);
        int rb = rel - bstart;
        float add = bf2f(c2p_t[w * 2112 + i16 * 132 + rb]) +
                    bf2f(p2c_t[rb * 66 + jb * 16 + lr]);
        s[jb][r] = (s[jb][r] + add) * CS;
      }
    }

    // ---- online softmax (per q-row; row lives in 16 lanes x 4 jb)
    float mx[4], fs[4];
    #pragma unroll
    for (int r = 0; r < 4; ++r) {
      float v = fmaxf(fmaxf(s[0][r], s[1][r]), fmaxf(s[2][r], s[3][r]));
      #pragma unroll
      for (int off = 1; off <= 8; off <<= 1) v = fmaxf(v, __shfl_xor(v, off));
      mx[r] = fmaxf(v, m_[r]);
      fs[r] = exp2f(m_[r] - mx[r]);
      m_[r] = mx[r];
    }
    #pragma unroll
    for (int jb = 0; jb < 4; ++jb)
      #pragma unroll
      for (int r = 0; r < 4; ++r)
        s[jb][r] = exp2f(s[jb][r] - mx[r]);
    #pragma unroll
    for (int r = 0; r < 4; ++r) {
      float v = s[0][r] + s[1][r] + s[2][r] + s[3][r];
      #pragma unroll
      for (int off = 1; off <= 8; off <<= 1) v += __shfl_xor(v, off);
      l_[r] = l_[r] * fs[r] + v;
    }
    #pragma unroll
    for (int db = 0; db < 4; ++db)
      #pragma unroll
      for (int r = 0; r < 4; ++r) ctx[db][r] *= fs[r];

    // ---- P -> LDS (overlay on pk_t rows 0..63), own-wave rows only
    #pragma unroll
    for (int jb = 0; jb < 4; ++jb) {
      #pragma unroll
      for (int r = 0; r < 4; ++r) {
        int row = w * 16 + 4 * lg + r, col = jb * 16 + lr;
        pk_t[row * 64 + (col ^ ((row & 7) << 3))] = f2bf(s[jb][r]);
      }
    }
    asm volatile("s_waitcnt lgkmcnt(0)" ::: "memory");  // wave-local write->read

    // ---- PV: ctx[db] += P * V ; V^T frags straight from global (L1/L2-hot)
    #pragma unroll
    for (int ks = 0; ks < 2; ++ks) {
      int row = w * 16 + lr, c0 = ks * 32 + 8 * lg;
      bf16x8 pa = __builtin_bit_cast(bf16x8,
          *(const u16x8*)(&pk_t[row * 64 + (c0 ^ ((row & 7) << 3))]));
      #pragma unroll
      for (int db = 0; db < 4; ++db) {
        bf16x8 vf = __builtin_bit_cast(bf16x8,
            *(const u16x8*)(vtbase + (db * 16 + lr) * S_LEN + j0 + ks * 32 + 8 * lg));
        ctx[db] = __builtin_amdgcn_mfma_f32_16x16x32_bf16(pa, vf, ctx[db], 0, 0, 0);
      }
    }
  }

  // ---- epilogue: out[b][i][h*64+d] = ctx / l
  #pragma unroll
  for (int r = 0; r < 4; ++r) {
    float inv = 1.0f / l_[r];
    int ig = itile * 64 + w * 16 + 4 * lg + r;
    float* orow = out + (b * S_LEN + ig) * 768 + h * 64;
    #pragma unroll
    for (int db = 0; db < 4; ++db)
      orow[db * 16 + lr] = ctx[db][r] * inv;
  }
}

extern "C" void kernel_launch(void* const* d_in, const int* in_sizes, int n_in,
                              void* d_out, int out_size, void* d_ws, size_t ws_size,
                              hipStream_t stream) {
  (void)in_sizes; (void)n_in; (void)out_size; (void)ws_size;
  const float* Hx  = (const float*)d_in[0];
  const float* pos = (const float*)d_in[1];
  // d_in[2] = relative_pos: deterministic (i-j), recomputed inline -> unused
  const float* Wq  = (const float*)d_in[3];  const float* bq  = (const float*)d_in[4];
  const float* Wk  = (const float*)d_in[5];  const float* bk  = (const float*)d_in[6];
  const float* Wv  = (const float*)d_in[7];  const float* bv  = (const float*)d_in[8];
  const float* Wpq = (const float*)d_in[9];  const float* bpq = (const float*)d_in[10];
  const float* Wpk = (const float*)d_in[11]; const float* bpk = (const float*)d_in[12];
  unsigned short* ws = (unsigned short*)d_ws;

  proj_kernel<<<640, 256, 0, stream>>>(Hx, pos, Wq, bq, Wk, bk, Wv, bv,
                                       Wpq, bpq, Wpk, bpk, ws);
  attn_kernel<<<768, 256, 0, stream>>>(ws, (float*)d_out);
}

// Round 2
// 349.171 us; speedup vs baseline: 1.5847x; 1.5847x over previous
//
#include <hip/hip_runtime.h>
#include <math.h>

// DeBERTa disentangled self-attention, fused (MI355X / gfx950).
// B=2, S=2048, D=64, H=12, K_SPAN=512.
// score[i,j] = (q_i.k_j + q_i.pk[c] + k_j.pq[c]) / sqrt(192), c = clip(i-j+512,0,1023)
//
// prep:      fp32 -> bf16 hi/lo split of H|pos, bf16 W, biases (scratch in d_out tail).
// proj_gemm: MFMA 16x16x32, X = hi+lo two-term product -> q/k/vT/pk/pq bf16 in ws.
// attn:      swapped-operand 32x32x16 flash attention:
//              s = mfma(K,Q)     -> lane owns score row  (i = lane&31)
//              position terms via diagonal-band MFMAs + 32KB LDS gather tables
//              softmax: 31 in-lane ops + 1 shfl_xor(32) per reduce
//              P repack: cvt-pack + shfl_xor(32) + select (no LDS round trip)
//              ctx = mfma(V,P)   -> lane owns ctx row    -> float4 stores

#define S_LEN 2048
#define NH    12
#define TWOK  1024
#define QSZ   3145728   // 24 * 2048 * 64
#define PSZ   786432    // 12 * 1024 * 64

typedef __bf16 bf16x8 __attribute__((ext_vector_type(8)));
typedef unsigned short u16x8 __attribute__((ext_vector_type(8)));
typedef float f32x4  __attribute__((ext_vector_type(4)));
typedef float f32x16 __attribute__((ext_vector_type(16)));
typedef unsigned int u32x2 __attribute__((ext_vector_type(2)));
typedef unsigned int u32x4 __attribute__((ext_vector_type(4)));

__device__ __forceinline__ unsigned short f2bf(float f) {
  return __builtin_bit_cast(unsigned short, (__bf16)f);
}
__device__ __forceinline__ unsigned pk2bf(float a, float b) {
  return ((unsigned)__builtin_bit_cast(unsigned short, (__bf16)b) << 16)
       | (unsigned)__builtin_bit_cast(unsigned short, (__bf16)a);
}
__device__ __forceinline__ float bf2f(unsigned short h) {
  return __builtin_bit_cast(float, ((unsigned)h) << 16);
}
__device__ __forceinline__ bf16x8 ld_bf8(const unsigned short* p) {
  return __builtin_bit_cast(bf16x8, *(const u16x8*)p);
}

// ---------------------------------------------------------------- prep
__global__ __launch_bounds__(256) void prep_kernel(
    const float* __restrict__ Hx, const float* __restrict__ pos,
    const float* __restrict__ Wq, const float* __restrict__ Wk,
    const float* __restrict__ Wv, const float* __restrict__ Wpk,
    const float* __restrict__ Wpq,
    const float* __restrict__ bq, const float* __restrict__ bk,
    const float* __restrict__ bv, const float* __restrict__ bpk,
    const float* __restrict__ bpq,
    unsigned short* __restrict__ whi, unsigned short* __restrict__ wlo,
    unsigned short* __restrict__ wall, float* __restrict__ ball) {
  int idx = blockIdx.x * 256 + threadIdx.x;
  if (idx < 327680) {                       // H (4096x64) then pos (1024x64): hi/lo split
    float v = (idx < 262144) ? Hx[idx] : pos[idx - 262144];
    __bf16 hi = (__bf16)v;
    float lo = v - (float)hi;
    whi[idx] = __builtin_bit_cast(unsigned short, hi);
    wlo[idx] = f2bf(lo);
  } else if (idx < 573440) {                // W: q,k,v,pk,pq -> bf16, 3840x64
    int k = idx - 327680;
    int mat = k / 49152, off = k - mat * 49152;
    const float* W = mat==0?Wq: mat==1?Wk: mat==2?Wv: mat==3?Wpk:Wpq;
    wall[k] = f2bf(W[off]);
  } else if (idx < 577280) {                // biases, 3840
    int k = idx - 573440;
    int mat = k / 768, off = k - mat * 768;
    const float* B = mat==0?bq: mat==1?bk: mat==2?bv: mat==3?bpk:bpq;
    ball[k] = B[off];
  }
}

// ---------------------------------------------------------------- projection GEMM
// block 256 = 4 waves; tile 64 rows x 64 oh; wave = 16 rows. X = hi + lo (2 MFMA/term).
__global__ __launch_bounds__(256) void proj_gemm(
    const unsigned short* __restrict__ whi, const unsigned short* __restrict__ wlo,
    const unsigned short* __restrict__ wall, const float* __restrict__ ball,
    unsigned short* __restrict__ ws) {
  unsigned short* qg  = ws;
  unsigned short* kg  = ws + QSZ;
  unsigned short* vtg = ws + 2 * QSZ;
  unsigned short* pkg = ws + 3 * QSZ;
  unsigned short* pqg = ws + 3 * QSZ + PSZ;

  int bid = blockIdx.x;
  int rbase, obase, wrow, isA;
  if (bid < 2304) { rbase = (bid / 36) * 64;        obase = (bid % 36) * 64; wrow = obase;        isA = 1; }
  else { int b2 = bid - 2304; rbase = 4096 + (b2 / 24) * 64; obase = (b2 % 24) * 64; wrow = 2304 + obase; isA = 0; }

  int tid = threadIdx.x, w = tid >> 6, l = tid & 63, lg = l >> 4, lr = l & 15;
  int xrow = rbase + w * 16 + lr;

  bf16x8 ah[2], al[2];
  #pragma unroll
  for (int ks = 0; ks < 2; ++ks) {
    ah[ks] = ld_bf8(whi + xrow * 64 + ks * 32 + 8 * lg);
    al[ks] = ld_bf8(wlo + xrow * 64 + ks * 32 + 8 * lg);
  }

  int mat = obase / 768;
  int h = ((obase % 768) >> 6);   // uniform per block (64-wide oh tile)

  #pragma unroll
  for (int jb = 0; jb < 4; ++jb) {
    f32x4 acc = {0.f, 0.f, 0.f, 0.f};
    #pragma unroll
    for (int ks = 0; ks < 2; ++ks) {
      bf16x8 bfrag = ld_bf8(wall + (wrow + jb * 16 + lr) * 64 + ks * 32 + 8 * lg);
      acc = __builtin_amdgcn_mfma_f32_16x16x32_bf16(ah[ks], bfrag, acc, 0, 0, 0);
      acc = __builtin_amdgcn_mfma_f32_16x16x32_bf16(al[ks], bfrag, acc, 0, 0, 0);
    }
    float bias = ball[wrow + jb * 16 + lr];
    int d = jb * 16 + lr;
    #pragma unroll
    for (int r = 0; r < 4; ++r) {
      int orow = rbase + w * 16 + 4 * lg + r;
      unsigned short val = f2bf(acc[r] + bias);
      if (isA) {
        int bb = orow >> 11, i = orow & 2047, bh = bb * NH + h;
        if (mat == 0)      qg[(bh * S_LEN + i) * 64 + d] = val;
        else if (mat == 1) kg[(bh * S_LEN + i) * 64 + d] = val;
        else               vtg[(bh * 64 + d) * S_LEN + i] = val;  // V transposed
      } else {
        int prow = orow - 4096;
        if (mat == 0) pkg[(h * TWOK + prow) * 64 + d] = val;
        else          pqg[(h * TWOK + prow) * 64 + d] = val;
      }
    }
  }
}

// ---------------------------------------------------------------- fused attention
// block = 128 thr (2 waves); block -> (bh, 64 q-rows); wave -> 32 q-rows.
// LDS 32KB: c2p table [2 waves][32 i][128 rel] + p2c table [64 j][128 rel], bf16,
// XOR-swizzled ((row&15)<<4), packed b64 writes.
__global__ __launch_bounds__(128, 2) void attn_kernel(
    const unsigned short* __restrict__ ws, float* __restrict__ out) {
  const unsigned short* qg  = ws;
  const unsigned short* kg  = ws + QSZ;
  const unsigned short* vtg = ws + 2 * QSZ;
  const unsigned short* pkg = ws + 3 * QSZ;
  const unsigned short* pqg = ws + 3 * QSZ + PSZ;

  __shared__ __align__(16) unsigned short tblC[2 * 32 * 128];
  __shared__ __align__(16) unsigned short tblP[64 * 128];

  const int bid = blockIdx.x;
  const int bh = bid >> 5, itile = bid & 31;
  const int b = bh / NH, h = bh - b * NH;
  const int tid = threadIdx.x;
  const int w = tid >> 6, l = tid & 63;
  const int iL = l & 31, h5 = l >> 5;

  const unsigned short* qb  = qg  + bh * (S_LEN * 64);
  const unsigned short* kb  = kg  + bh * (S_LEN * 64);
  const unsigned short* vb  = vtg + bh * (64 * S_LEN);
  const unsigned short* pkb = pkg + h * (TWOK * 64);
  const unsigned short* pqb = pqg + h * (TWOK * 64);

  const float CS = 1.4426950408889634f / sqrtf(192.0f);  // log2(e)/sqrt(3*64)

  // Q as B-frag: lane holds Q[col=i=iL][k = kc*16 + 8*h5 + e]
  const int ig = itile * 64 + w * 32 + iL;
  bf16x8 qf[4];
  #pragma unroll
  for (int kc = 0; kc < 4; ++kc)
    qf[kc] = ld_bf8(qb + ig * 64 + kc * 16 + 8 * h5);

  f32x16 ctx0 = 0.f, ctx1 = 0.f;
  float m_ = -1e30f, l_ = 0.f;

  char* tC = (char*)tblC;
  char* tP = (char*)tblP;
  char* cbase = tC + (w * 32 + iL) * 256;          // this lane's c2p row (i-row)
  const int cxor = (iL & 15) << 4;
  const int prow = w * 32 + iL;                    // this lane's p2c row (j-row)
  char* pbase = tP + prow * 256;
  const int pxor = (prow & 15) << 4;

  for (int jt = 0; jt < 32; ++jt) {
    const int j0 = jt * 64;
    int R0 = itile * 64 - j0 + 512;
    int relmin = R0 - 63; relmin = relmin < 0 ? 0 : (relmin > 1023 ? 1023 : relmin);
    int relmax = R0 + 63; relmax = relmax < 0 ? 0 : (relmax > 1023 ? 1023 : relmax);
    int bstart = relmin > 896 ? 896 : relmin;
    int nb_lo = (relmin - bstart) >> 5, nb_hi = (relmax - bstart) >> 5;

    // K as A-frag: lane holds K[row=j][k]; both 32-row subtiles
    bf16x8 kf0[4], kf1[4];
    #pragma unroll
    for (int kc = 0; kc < 4; ++kc) {
      kf0[kc] = ld_bf8(kb + (j0 + iL) * 64 + kc * 16 + 8 * h5);
      kf1[kc] = ld_bf8(kb + (j0 + 32 + iL) * 64 + kc * 16 + 8 * h5);
    }
    // QK^T swapped: D[row=j][col=i]; lane: i=iL, j = 32*js + (r&3)+8*(r>>2)+4*h5
    f32x16 s0 = 0.f, s1 = 0.f;
    #pragma unroll
    for (int kc = 0; kc < 4; ++kc) {
      s0 = __builtin_amdgcn_mfma_f32_32x32x16_bf16(kf0[kc], qf[kc], s0, 0, 0, 0);
      s1 = __builtin_amdgcn_mfma_f32_32x32x16_bf16(kf1[kc], qf[kc], s1, 0, 0, 0);
    }
    // own wave's K subtile, reused as B-operand (col=j) for p2c
    bf16x8 kp[4];
    #pragma unroll
    for (int kc = 0; kc < 4; ++kc) kp[kc] = w ? kf1[kc] : kf0[kc];

    __syncthreads();   // B1: prior iteration's gathers complete

    // diagonal bands -> tables.  c2p = mfma(pk,Q): D[row=rel][col=i];
    // p2c = mfma(pq,K): D[row=rel][col=j].  Packed b64 writes, consecutive rel.
    for (int nb = nb_lo; nb <= nb_hi; ++nb) {
      const int rrow = bstart + nb * 32 + iL;
      f32x16 ac = 0.f, ap = 0.f;
      #pragma unroll
      for (int kc = 0; kc < 4; ++kc) {
        bf16x8 fk = ld_bf8(pkb + rrow * 64 + kc * 16 + 8 * h5);
        bf16x8 fq = ld_bf8(pqb + rrow * 64 + kc * 16 + 8 * h5);
        ac = __builtin_amdgcn_mfma_f32_32x32x16_bf16(fk, qf[kc], ac, 0, 0, 0);
        ap = __builtin_amdgcn_mfma_f32_32x32x16_bf16(fq, kp[kc], ap, 0, 0, 0);
      }
      #pragma unroll
      for (int q4 = 0; q4 < 4; ++q4) {
        int relb = 32 * nb + 8 * q4 + 4 * h5;   // 4 consecutive rel per reg quad
        u32x2 vc; vc[0] = pk2bf(ac[4*q4+0], ac[4*q4+1]); vc[1] = pk2bf(ac[4*q4+2], ac[4*q4+3]);
        *(u32x2*)(cbase + ((relb * 2) ^ cxor)) = vc;
        u32x2 vp; vp[0] = pk2bf(ap[4*q4+0], ap[4*q4+1]); vp[1] = pk2bf(ap[4*q4+2], ap[4*q4+3]);
        *(u32x2*)(pbase + ((relb * 2) ^ pxor)) = vp;
      }
    }
    __syncthreads();   // B2: tables ready (p2c is cross-wave)

    // gather + scale into exp2 domain
    const int D0 = ig + 512 - j0;
    #pragma unroll
    for (int r = 0; r < 16; ++r) {
      const int j32 = (r & 3) + 8 * (r >> 2) + 4 * h5;
      {
        int rel = D0 - j32; rel = rel < 0 ? 0 : (rel > 1023 ? 1023 : rel);
        int rb = rel - bstart;
        float c2 = bf2f(*(const unsigned short*)(cbase + ((rb * 2) ^ cxor)));
        float p2 = bf2f(*(const unsigned short*)(tP + j32 * 256 + ((rb * 2) ^ ((j32 & 15) << 4))));
        s0[r] = (s0[r] + c2 + p2) * CS;
      }
      {
        int jl = 32 + j32;
        int rel = D0 - jl; rel = rel < 0 ? 0 : (rel > 1023 ? 1023 : rel);
        int rb = rel - bstart;
        float c2 = bf2f(*(const unsigned short*)(cbase + ((rb * 2) ^ cxor)));
        float p2 = bf2f(*(const unsigned short*)(tP + jl * 256 + ((rb * 2) ^ ((jl & 15) << 4))));
        s1[r] = (s1[r] + c2 + p2) * CS;
      }
    }

    // online softmax: lane owns full row i; 31 in-lane + 1 cross-half op per reduce
    float vmax = s0[0];
    #pragma unroll
    for (int r = 1; r < 16; ++r) vmax = fmaxf(vmax, s0[r]);
    #pragma unroll
    for (int r = 0; r < 16; ++r) vmax = fmaxf(vmax, s1[r]);
    vmax = fmaxf(vmax, __shfl_xor(vmax, 32));
    float mx = fmaxf(m_, vmax);
    float fs = __builtin_amdgcn_exp2f(m_ - mx);
    m_ = mx;
    float sum = 0.f;
    #pragma unroll
    for (int r = 0; r < 16; ++r) { s0[r] = __builtin_amdgcn_exp2f(s0[r] - mx); sum += s0[r]; }
    #pragma unroll
    for (int r = 0; r < 16; ++r) { s1[r] = __builtin_amdgcn_exp2f(s1[r] - mx); sum += s1[r]; }
    sum += __shfl_xor(sum, 32);
    l_ = l_ * fs + sum;
    ctx0 *= fs; ctx1 *= fs;

    // repack P -> B-frags for PV: cvt-pack + cross-half shfl + select
    bf16x8 pf[4];
    #pragma unroll
    for (int kc = 0; kc < 4; ++kc) {
      const int c = kc & 1;
      const f32x16& sj = (kc >> 1) ? s1 : s0;     // compile-time select
      unsigned X0 = pk2bf(sj[8*c+0], sj[8*c+1]);
      unsigned X1 = pk2bf(sj[8*c+2], sj[8*c+3]);
      unsigned Y0 = pk2bf(sj[8*c+4], sj[8*c+5]);
      unsigned Y1 = pk2bf(sj[8*c+6], sj[8*c+7]);
      unsigned sx0 = (unsigned)__shfl_xor((int)X0, 32);
      unsigned sx1 = (unsigned)__shfl_xor((int)X1, 32);
      unsigned sy0 = (unsigned)__shfl_xor((int)Y0, 32);
      unsigned sy1 = (unsigned)__shfl_xor((int)Y1, 32);
      u32x4 f;
      f[0] = h5 ? sy0 : X0;
      f[1] = h5 ? sy1 : X1;
      f[2] = h5 ? Y0 : sx0;
      f[3] = h5 ? Y1 : sx1;
      pf[kc] = __builtin_bit_cast(bf16x8, f);
    }

    // PV: ctx = mfma(A=V^T rows d, B=P col i) -> D[row=d][col=i]; lane owns ctx row i
    #pragma unroll
    for (int kc = 0; kc < 4; ++kc) {
      bf16x8 v0 = ld_bf8(vb + (iL) * S_LEN + j0 + kc * 16 + 8 * h5);
      bf16x8 v1 = ld_bf8(vb + (32 + iL) * S_LEN + j0 + kc * 16 + 8 * h5);
      ctx0 = __builtin_amdgcn_mfma_f32_32x32x16_bf16(v0, pf[kc], ctx0, 0, 0, 0);
      ctx1 = __builtin_amdgcn_mfma_f32_32x32x16_bf16(v1, pf[kc], ctx1, 0, 0, 0);
    }
  }

  // epilogue: lane owns row i = ig; d = 32*ds + 8*q4 + 4*h5 + (0..3) -> float4 stores
  float inv = 1.0f / l_;
  float* ob = out + (b * S_LEN + ig) * 768 + h * 64;
  #pragma unroll
  for (int q4 = 0; q4 < 4; ++q4) {
    float4 o0 = {ctx0[4*q4+0]*inv, ctx0[4*q4+1]*inv, ctx0[4*q4+2]*inv, ctx0[4*q4+3]*inv};
    *(float4*)(ob + 8 * q4 + 4 * h5) = o0;
    float4 o1 = {ctx1[4*q4+0]*inv, ctx1[4*q4+1]*inv, ctx1[4*q4+2]*inv, ctx1[4*q4+3]*inv};
    *(float4*)(ob + 32 + 8 * q4 + 4 * h5) = o1;
  }
}

extern "C" void kernel_launch(void* const* d_in, const int* in_sizes, int n_in,
                              void* d_out, int out_size, void* d_ws, size_t ws_size,
                              hipStream_t stream) {
  (void)in_sizes; (void)n_in; (void)out_size; (void)ws_size;
  const float* Hx  = (const float*)d_in[0];
  const float* pos = (const float*)d_in[1];
  // d_in[2] = relative_pos: deterministic (i-j), recomputed inline -> unused
  const float* Wq  = (const float*)d_in[3];  const float* bq  = (const float*)d_in[4];
  const float* Wk  = (const float*)d_in[5];  const float* bk  = (const float*)d_in[6];
  const float* Wv  = (const float*)d_in[7];  const float* bv  = (const float*)d_in[8];
  const float* Wpq = (const float*)d_in[9];  const float* bpq = (const float*)d_in[10];
  const float* Wpk = (const float*)d_in[11]; const float* bpk = (const float*)d_in[12];
  unsigned short* ws = (unsigned short*)d_ws;

  // prep scratch lives in d_out's head (12.58MB; attn rewrites all of d_out later)
  unsigned short* scratch = (unsigned short*)d_out;
  unsigned short* whi  = scratch;            // 327680 u16
  unsigned short* wlo  = scratch + 327680;   // 327680 u16
  unsigned short* wall = scratch + 655360;   // 245760 u16
  float*          ball = (float*)(scratch + 901120);  // 3840 f32

  prep_kernel<<<2255, 256, 0, stream>>>(Hx, pos, Wq, Wk, Wv, Wpk, Wpq,
                                        bq, bk, bv, bpk, bpq, whi, wlo, wall, ball);
  proj_gemm<<<2688, 256, 0, stream>>>(whi, wlo, wall, ball, ws);
  attn_kernel<<<768, 128, 0, stream>>>(ws, (float*)d_out);
}

// Round 3
// 345.495 us; speedup vs baseline: 1.6016x; 1.0106x over previous
//
#include <hip/hip_runtime.h>
#include <math.h>

// DeBERTa disentangled self-attention, fused (MI355X / gfx950).
// B=2, S=2048, D=64, H=12, K_SPAN=512.
// score[i,j] = (q_i.k_j + q_i.pk[c] + k_j.pq[c]) / sqrt(192), c = clip(i-j+512,0,1023)
//
// prep:      fp32 -> bf16 hi/lo split of H|pos, bf16 W, biases (scratch in d_out head).
// proj_gemm: MFMA 16x16x32, X = hi+lo two-term product -> q/k/vT/pk/pq bf16 in ws.
// pos_dots:  c2p0/1023[bh][i] = q.pk[0/1023];  p2c0/1023[bh][j] = k.pq[0/1023].
// attn:      barrier-free swapped-operand 32x32x16 flash attention; 2 independent
//            waves/block, private LDS tables; fully-clamped jt fast path uses the
//            pos_dots vectors (no bands, no gathers); interior jts use tight
//            per-wave diagonal bands + clamp-free gathers.

#define S_LEN 2048
#define NH    12
#define TWOK  1024
#define QSZ   3145728   // 24 * 2048 * 64
#define PSZ   786432    // 12 * 1024 * 64
#define POSF  11010048  // 3*QSZ + 2*PSZ (u16 elements)

typedef __bf16 bf16x8 __attribute__((ext_vector_type(8)));
typedef unsigned short u16x8 __attribute__((ext_vector_type(8)));
typedef float f32x4  __attribute__((ext_vector_type(4)));
typedef float f32x16 __attribute__((ext_vector_type(16)));
typedef unsigned int u32x2 __attribute__((ext_vector_type(2)));
typedef unsigned int u32x4 __attribute__((ext_vector_type(4)));

__device__ __forceinline__ unsigned short f2bf(float f) {
  return __builtin_bit_cast(unsigned short, (__bf16)f);
}
__device__ __forceinline__ unsigned pk2bf(float a, float b) {
  return ((unsigned)__builtin_bit_cast(unsigned short, (__bf16)b) << 16)
       | (unsigned)__builtin_bit_cast(unsigned short, (__bf16)a);
}
__device__ __forceinline__ float bf2f(unsigned short h) {
  return __builtin_bit_cast(float, ((unsigned)h) << 16);
}
__device__ __forceinline__ bf16x8 ld_bf8(const unsigned short* p) {
  return __builtin_bit_cast(bf16x8, *(const u16x8*)p);
}

// ---------------------------------------------------------------- prep
__global__ __launch_bounds__(256) void prep_kernel(
    const float* __restrict__ Hx, const float* __restrict__ pos,
    const float* __restrict__ Wq, const float* __restrict__ Wk,
    const float* __restrict__ Wv, const float* __restrict__ Wpk,
    const float* __restrict__ Wpq,
    const float* __restrict__ bq, const float* __restrict__ bk,
    const float* __restrict__ bv, const float* __restrict__ bpk,
    const float* __restrict__ bpq,
    unsigned short* __restrict__ whi, unsigned short* __restrict__ wlo,
    unsigned short* __restrict__ wall, float* __restrict__ ball) {
  int idx = blockIdx.x * 256 + threadIdx.x;
  if (idx < 327680) {                       // H (4096x64) then pos (1024x64): hi/lo split
    float v = (idx < 262144) ? Hx[idx] : pos[idx - 262144];
    __bf16 hi = (__bf16)v;
    float lo = v - (float)hi;
    whi[idx] = __builtin_bit_cast(unsigned short, hi);
    wlo[idx] = f2bf(lo);
  } else if (idx < 573440) {                // W: q,k,v,pk,pq -> bf16, 3840x64
    int k = idx - 327680;
    int mat = k / 49152, off = k - mat * 49152;
    const float* W = mat==0?Wq: mat==1?Wk: mat==2?Wv: mat==3?Wpk:Wpq;
    wall[k] = f2bf(W[off]);
  } else if (idx < 577280) {                // biases, 3840
    int k = idx - 573440;
    int mat = k / 768, off = k - mat * 768;
    const float* B = mat==0?bq: mat==1?bk: mat==2?bv: mat==3?bpk:bpq;
    ball[k] = B[off];
  }
}

// ---------------------------------------------------------------- projection GEMM
__global__ __launch_bounds__(256) void proj_gemm(
    const unsigned short* __restrict__ whi, const unsigned short* __restrict__ wlo,
    const unsigned short* __restrict__ wall, const float* __restrict__ ball,
    unsigned short* __restrict__ ws) {
  unsigned short* qg  = ws;
  unsigned short* kg  = ws + QSZ;
  unsigned short* vtg = ws + 2 * QSZ;
  unsigned short* pkg = ws + 3 * QSZ;
  unsigned short* pqg = ws + 3 * QSZ + PSZ;

  int bid = blockIdx.x;
  int rbase, obase, wrow, isA;
  if (bid < 2304) { rbase = (bid / 36) * 64;        obase = (bid % 36) * 64; wrow = obase;        isA = 1; }
  else { int b2 = bid - 2304; rbase = 4096 + (b2 / 24) * 64; obase = (b2 % 24) * 64; wrow = 2304 + obase; isA = 0; }

  int tid = threadIdx.x, w = tid >> 6, l = tid & 63, lg = l >> 4, lr = l & 15;
  int xrow = rbase + w * 16 + lr;

  bf16x8 ah[2], al[2];
  #pragma unroll
  for (int ks = 0; ks < 2; ++ks) {
    ah[ks] = ld_bf8(whi + xrow * 64 + ks * 32 + 8 * lg);
    al[ks] = ld_bf8(wlo + xrow * 64 + ks * 32 + 8 * lg);
  }

  int mat = obase / 768;
  int h = ((obase % 768) >> 6);   // uniform per block

  #pragma unroll
  for (int jb = 0; jb < 4; ++jb) {
    f32x4 acc = {0.f, 0.f, 0.f, 0.f};
    #pragma unroll
    for (int ks = 0; ks < 2; ++ks) {
      bf16x8 bfrag = ld_bf8(wall + (wrow + jb * 16 + lr) * 64 + ks * 32 + 8 * lg);
      acc = __builtin_amdgcn_mfma_f32_16x16x32_bf16(ah[ks], bfrag, acc, 0, 0, 0);
      acc = __builtin_amdgcn_mfma_f32_16x16x32_bf16(al[ks], bfrag, acc, 0, 0, 0);
    }
    float bias = ball[wrow + jb * 16 + lr];
    int d = jb * 16 + lr;
    #pragma unroll
    for (int r = 0; r < 4; ++r) {
      int orow = rbase + w * 16 + 4 * lg + r;
      unsigned short val = f2bf(acc[r] + bias);
      if (isA) {
        int bb = orow >> 11, i = orow & 2047, bh = bb * NH + h;
        if (mat == 0)      qg[(bh * S_LEN + i) * 64 + d] = val;
        else if (mat == 1) kg[(bh * S_LEN + i) * 64 + d] = val;
        else               vtg[(bh * 64 + d) * S_LEN + i] = val;  // V transposed
      } else {
        int prow = orow - 4096;
        if (mat == 0) pkg[(h * TWOK + prow) * 64 + d] = val;
        else          pqg[(h * TWOK + prow) * 64 + d] = val;
      }
    }
  }
}

// ---------------------------------------------------------------- pos_dots
// c2p0/1023[bh*2048+i] = q_i . pk[0/1023];  p2c0/1023[bh*2048+j] = k_j . pq[0/1023]
__global__ __launch_bounds__(256) void pos_dots(
    const unsigned short* __restrict__ ws, float* __restrict__ c2p0,
    float* __restrict__ c2p1023, float* __restrict__ p2c0,
    float* __restrict__ p2c1023) {
  int t = blockIdx.x * 256 + threadIdx.x;     // [0, 98304)
  int isK = t >= 49152;
  int row = isK ? t - 49152 : t;              // bh*2048 + i
  int h = (row >> 11) % NH;
  const unsigned short* src = ws + (isK ? QSZ : 0) + row * 64;
  const unsigned short* pA = ws + 3 * QSZ + (isK ? PSZ : 0) + (h * TWOK) * 64;
  const unsigned short* pB = pA + 1023 * 64;
  float a0 = 0.f, a1 = 0.f;
  #pragma unroll
  for (int c = 0; c < 8; ++c) {
    u16x8 xv = *(const u16x8*)(src + c * 8);
    u16x8 av = *(const u16x8*)(pA + c * 8);
    u16x8 bv = *(const u16x8*)(pB + c * 8);
    #pragma unroll
    for (int e = 0; e < 8; ++e) {
      float x = bf2f(xv[e]);
      a0 += x * bf2f(av[e]);
      a1 += x * bf2f(bv[e]);
    }
  }
  if (isK) { p2c0[row] = a0; p2c1023[row] = a1; }
  else     { c2p0[row] = a0; c2p1023[row] = a1; }
}

// ---------------------------------------------------------------- fused attention
// 128 thr = 2 INDEPENDENT waves (no __syncthreads). Wave owns 32 q-rows + private
// LDS tables: c2p[32][128], p2c[64][128] bf16, XOR-swizzled ((row&15)<<4).
__global__ __launch_bounds__(128, 2) void attn_kernel(
    const unsigned short* __restrict__ ws, float* __restrict__ out) {
  const unsigned short* qg  = ws;
  const unsigned short* kg  = ws + QSZ;
  const unsigned short* vtg = ws + 2 * QSZ;
  const unsigned short* pkg = ws + 3 * QSZ;
  const unsigned short* pqg = ws + 3 * QSZ + PSZ;
  const float* c2p0g    = (const float*)(ws + POSF);
  const float* c2p1023g = c2p0g + 49152;
  const float* p2c0g    = c2p0g + 98304;
  const float* p2c1023g = c2p0g + 147456;

  __shared__ __align__(16) unsigned short tblC[2 * 32 * 128];
  __shared__ __align__(16) unsigned short tblP[2 * 64 * 128];

  const int bid = blockIdx.x;
  const int bh = bid >> 5, itile = bid & 31;
  const int b = bh / NH, h = bh - b * NH;
  const int tid = threadIdx.x;
  const int w = tid >> 6, l = tid & 63;
  const int iL = l & 31, h5 = l >> 5;
  const int i0w = itile * 64 + w * 32;
  const int ig = i0w + iL;

  const unsigned short* qb  = qg  + bh * (S_LEN * 64);
  const unsigned short* kb  = kg  + bh * (S_LEN * 64);
  const unsigned short* vb  = vtg + bh * (64 * S_LEN);
  const unsigned short* pkb = pkg + h * (TWOK * 64);
  const unsigned short* pqb = pqg + h * (TWOK * 64);

  const float CS = 1.4426950408889634f / sqrtf(192.0f);  // log2(e)/sqrt(3*64)

  // Q as B-frag: lane holds Q[col=i=iL][k = kc*16 + 8*h5 + e]
  bf16x8 qf[4];
  #pragma unroll
  for (int kc = 0; kc < 4; ++kc)
    qf[kc] = ld_bf8(qb + ig * 64 + kc * 16 + 8 * h5);

  const float c2pLO = c2p0g[bh * S_LEN + ig];
  const float c2pHI = c2p1023g[bh * S_LEN + ig];

  f32x16 ctx0 = 0.f, ctx1 = 0.f;
  float m_ = -1e30f, l_ = 0.f;

  char* cbase = (char*)tblC + w * 8192 + iL * 256;   // own c2p row (i)
  char* tPw   = (char*)tblP + w * 16384;
  char* pb0   = tPw + iL * 256;                      // own p2c rows (j=iL, 32+iL)
  char* pb1   = tPw + (32 + iL) * 256;
  const int cxor = (iL & 15) << 4;                   // same for all three rows

  for (int jt = 0; jt < 32; ++jt) {
    const int j0 = jt * 64;
    const int rlo = 512 + i0w - j0 - 63;   // unclipped min rel over wave tile
    const int rhi = rlo + 94;              // unclipped max

    // K as A-frag (rows j) - also reused as B-frag (cols j) for p2c bands
    bf16x8 kf0[4], kf1[4];
    #pragma unroll
    for (int kc = 0; kc < 4; ++kc) {
      kf0[kc] = ld_bf8(kb + (j0 + iL) * 64 + kc * 16 + 8 * h5);
      kf1[kc] = ld_bf8(kb + (j0 + 32 + iL) * 64 + kc * 16 + 8 * h5);
    }
    // QK^T swapped: D[row=j][col=i]; lane: i=iL, j = 32*js + (r&3)+8*(r>>2)+4*h5
    f32x16 s0 = 0.f, s1 = 0.f;
    #pragma unroll
    for (int kc = 0; kc < 4; ++kc) {
      s0 = __builtin_amdgcn_mfma_f32_32x32x16_bf16(kf0[kc], qf[kc], s0, 0, 0, 0);
      s1 = __builtin_amdgcn_mfma_f32_32x32x16_bf16(kf1[kc], qf[kc], s1, 0, 0, 0);
    }

    if (rlo >= 1023) {
      // -------- fully clamped high: add = c2p1023[i] + p2c1023[j]
      float pa = p2c1023g[bh * S_LEN + j0 + iL];
      float pb = p2c1023g[bh * S_LEN + j0 + 32 + iL];
      #pragma unroll
      for (int r = 0; r < 16; ++r) {
        const int j32 = (r & 3) + 8 * (r >> 2) + 4 * h5;
        s0[r] = (s0[r] + c2pHI + __shfl(pa, j32)) * CS;
        s1[r] = (s1[r] + c2pHI + __shfl(pb, j32)) * CS;
      }
    } else if (rhi <= 0) {
      // -------- fully clamped low: add = c2p0[i] + p2c0[j]
      float pa = p2c0g[bh * S_LEN + j0 + iL];
      float pb = p2c0g[bh * S_LEN + j0 + 32 + iL];
      #pragma unroll
      for (int r = 0; r < 16; ++r) {
        const int j32 = (r & 3) + 8 * (r >> 2) + 4 * h5;
        s0[r] = (s0[r] + c2pLO + __shfl(pa, j32)) * CS;
        s1[r] = (s1[r] + c2pLO + __shfl(pb, j32)) * CS;
      }
    } else {
      // -------- banded path
      const int rminc = rlo < 0 ? 0 : rlo;
      const int rmaxc = rhi > 1023 ? 1023 : rhi;
      const int bstart = rminc > 928 ? 928 : rminc;
      const int nbh = (rmaxc - bstart) >> 5;         // <= 2
      const int interior = (rlo >= 0) & (rhi <= 1023);
      int c_lo = (rminc - bstart) >> 5;
      int p0_lo, p1_hi;
      if (interior) {
        p0_lo = (rlo + 32 - bstart) >> 5;
        p1_hi = (rhi - 32 - bstart) >> 5;
      } else { p0_lo = c_lo; p1_hi = nbh; }

      // bands -> tables (prior gathers already consumed => LDS reuse safe)
      for (int nb = c_lo; nb <= nbh; ++nb) {
        const int rrow = bstart + nb * 32 + iL;
        const int doP0 = nb >= p0_lo, doP1 = nb <= p1_hi;
        f32x16 ac = 0.f, a0 = 0.f, a1 = 0.f;
        #pragma unroll
        for (int kc = 0; kc < 4; ++kc) {
          bf16x8 fk = ld_bf8(pkb + rrow * 64 + kc * 16 + 8 * h5);
          ac = __builtin_amdgcn_mfma_f32_32x32x16_bf16(fk, qf[kc], ac, 0, 0, 0);
        }
        if (doP0 | doP1) {
          #pragma unroll
          for (int kc = 0; kc < 4; ++kc) {
            bf16x8 fq = ld_bf8(pqb + rrow * 64 + kc * 16 + 8 * h5);
            if (doP0) a0 = __builtin_amdgcn_mfma_f32_32x32x16_bf16(fq, kf0[kc], a0, 0, 0, 0);
            if (doP1) a1 = __builtin_amdgcn_mfma_f32_32x32x16_bf16(fq, kf1[kc], a1, 0, 0, 0);
          }
        }
        #pragma unroll
        for (int q4 = 0; q4 < 4; ++q4) {
          const int off = ((nb * 32 + 8 * q4 + 4 * h5) * 2) ^ cxor;
          u32x2 vc; vc[0] = pk2bf(ac[4*q4+0], ac[4*q4+1]); vc[1] = pk2bf(ac[4*q4+2], ac[4*q4+3]);
          *(u32x2*)(cbase + off) = vc;
          if (doP0) {
            u32x2 v0; v0[0] = pk2bf(a0[4*q4+0], a0[4*q4+1]); v0[1] = pk2bf(a0[4*q4+2], a0[4*q4+3]);
            *(u32x2*)(pb0 + off) = v0;
          }
          if (doP1) {
            u32x2 v1; v1[0] = pk2bf(a1[4*q4+0], a1[4*q4+1]); v1[1] = pk2bf(a1[4*q4+2], a1[4*q4+3]);
            *(u32x2*)(pb1 + off) = v1;
          }
        }
      }
      asm volatile("s_waitcnt lgkmcnt(0)" ::: "memory");  // wave-local write->read

      const int D0 = ig + 512 - j0;
      if (interior) {
        // clamp-free gathers; rb = D0 - bstart - j
        const int t0 = (D0 - bstart) * 2;
        #pragma unroll
        for (int r = 0; r < 16; ++r) {
          const int j32 = (r & 3) + 8 * (r >> 2) + 4 * h5;
          const int pxr = (j32 & 15) << 4;                  // == ((32+j32)&15)<<4
          const int o0 = t0 - 2 * j32, o1 = o0 - 64;
          float c0v = bf2f(*(const unsigned short*)(cbase + (o0 ^ cxor)));
          float p0v = bf2f(*(const unsigned short*)(tPw + j32 * 256 + (o0 ^ pxr)));
          float c1v = bf2f(*(const unsigned short*)(cbase + (o1 ^ cxor)));
          float p1v = bf2f(*(const unsigned short*)(tPw + (32 + j32) * 256 + (o1 ^ pxr)));
          s0[r] = (s0[r] + c0v + p0v) * CS;
          s1[r] = (s1[r] + c1v + p1v) * CS;
        }
      } else {
        #pragma unroll
        for (int r = 0; r < 16; ++r) {
          const int j32 = (r & 3) + 8 * (r >> 2) + 4 * h5;
          const int pxr = (j32 & 15) << 4;
          int rel0 = D0 - j32;       rel0 = rel0 < 0 ? 0 : (rel0 > 1023 ? 1023 : rel0);
          int rel1 = D0 - 32 - j32;  rel1 = rel1 < 0 ? 0 : (rel1 > 1023 ? 1023 : rel1);
          const int o0 = (rel0 - bstart) * 2, o1 = (rel1 - bstart) * 2;
          float c0v = bf2f(*(const unsigned short*)(cbase + (o0 ^ cxor)));
          float p0v = bf2f(*(const unsigned short*)(tPw + j32 * 256 + (o0 ^ pxr)));
          float c1v = bf2f(*(const unsigned short*)(cbase + (o1 ^ cxor)));
          float p1v = bf2f(*(const unsigned short*)(tPw + (32 + j32) * 256 + (o1 ^ pxr)));
          s0[r] = (s0[r] + c0v + p0v) * CS;
          s1[r] = (s1[r] + c1v + p1v) * CS;
        }
      }
    }

    // -------- online softmax (lane owns full row i)
    float vmax = s0[0];
    #pragma unroll
    for (int r = 1; r < 16; ++r) vmax = fmaxf(vmax, s0[r]);
    #pragma unroll
    for (int r = 0; r < 16; ++r) vmax = fmaxf(vmax, s1[r]);
    vmax = fmaxf(vmax, __shfl_xor(vmax, 32));
    float mx = fmaxf(m_, vmax);
    float fs = __builtin_amdgcn_exp2f(m_ - mx);
    m_ = mx;
    float sum = 0.f;
    #pragma unroll
    for (int r = 0; r < 16; ++r) { s0[r] = __builtin_amdgcn_exp2f(s0[r] - mx); sum += s0[r]; }
    #pragma unroll
    for (int r = 0; r < 16; ++r) { s1[r] = __builtin_amdgcn_exp2f(s1[r] - mx); sum += s1[r]; }
    sum += __shfl_xor(sum, 32);
    l_ = l_ * fs + sum;
    if (!__all(fs == 1.0f)) { ctx0 *= fs; ctx1 *= fs; }   // defer-rescale (exact)

    // -------- repack P -> B-frags: cvt-pack + cross-half shfl + select
    bf16x8 pf[4];
    #pragma unroll
    for (int kc = 0; kc < 4; ++kc) {
      const int c = kc & 1;
      const f32x16& sj = (kc >> 1) ? s1 : s0;
      unsigned X0 = pk2bf(sj[8*c+0], sj[8*c+1]);
      unsigned X1 = pk2bf(sj[8*c+2], sj[8*c+3]);
      unsigned Y0 = pk2bf(sj[8*c+4], sj[8*c+5]);
      unsigned Y1 = pk2bf(sj[8*c+6], sj[8*c+7]);
      unsigned sx0 = (unsigned)__shfl_xor((int)X0, 32);
      unsigned sx1 = (unsigned)__shfl_xor((int)X1, 32);
      unsigned sy0 = (unsigned)__shfl_xor((int)Y0, 32);
      unsigned sy1 = (unsigned)__shfl_xor((int)Y1, 32);
      u32x4 f;
      f[0] = h5 ? sy0 : X0;
      f[1] = h5 ? sy1 : X1;
      f[2] = h5 ? Y0 : sx0;
      f[3] = h5 ? Y1 : sx1;
      pf[kc] = __builtin_bit_cast(bf16x8, f);
    }

    // -------- PV: ctx = mfma(V^T, P) -> D[row=d][col=i]; lane owns ctx row i
    #pragma unroll
    for (int kc = 0; kc < 4; ++kc) {
      bf16x8 v0 = ld_bf8(vb + (iL) * S_LEN + j0 + kc * 16 + 8 * h5);
      bf16x8 v1 = ld_bf8(vb + (32 + iL) * S_LEN + j0 + kc * 16 + 8 * h5);
      ctx0 = __builtin_amdgcn_mfma_f32_32x32x16_bf16(v0, pf[kc], ctx0, 0, 0, 0);
      ctx1 = __builtin_amdgcn_mfma_f32_32x32x16_bf16(v1, pf[kc], ctx1, 0, 0, 0);
    }
  }

  // -------- epilogue: lane owns row i = ig -> float4 stores
  float inv = 1.0f / l_;
  float* ob = out + (b * S_LEN + ig) * 768 + h * 64;
  #pragma unroll
  for (int q4 = 0; q4 < 4; ++q4) {
    float4 o0 = {ctx0[4*q4+0]*inv, ctx0[4*q4+1]*inv, ctx0[4*q4+2]*inv, ctx0[4*q4+3]*inv};
    *(float4*)(ob + 8 * q4 + 4 * h5) = o0;
    float4 o1 = {ctx1[4*q4+0]*inv, ctx1[4*q4+1]*inv, ctx1[4*q4+2]*inv, ctx1[4*q4+3]*inv};
    *(float4*)(ob + 32 + 8 * q4 + 4 * h5) = o1;
  }
}

extern "C" void kernel_launch(void* const* d_in, const int* in_sizes, int n_in,
                              void* d_out, int out_size, void* d_ws, size_t ws_size,
                              hipStream_t stream) {
  (void)in_sizes; (void)n_in; (void)out_size; (void)ws_size;
  const float* Hx  = (const float*)d_in[0];
  const float* pos = (const float*)d_in[1];
  // d_in[2] = relative_pos: deterministic (i-j), recomputed inline -> unused
  const float* Wq  = (const float*)d_in[3];  const float* bq  = (const float*)d_in[4];
  const float* Wk  = (const float*)d_in[5];  const float* bk  = (const float*)d_in[6];
  const float* Wv  = (const float*)d_in[7];  const float* bv  = (const float*)d_in[8];
  const float* Wpq = (const float*)d_in[9];  const float* bpq = (const float*)d_in[10];
  const float* Wpk = (const float*)d_in[11]; const float* bpk = (const float*)d_in[12];
  unsigned short* ws = (unsigned short*)d_ws;

  // prep scratch lives in d_out's head (attn rewrites all of d_out later)
  unsigned short* scratch = (unsigned short*)d_out;
  unsigned short* whi  = scratch;            // 327680 u16
  unsigned short* wlo  = scratch + 327680;   // 327680 u16
  unsigned short* wall = scratch + 655360;   // 245760 u16
  float*          ball = (float*)(scratch + 901120);  // 3840 f32

  float* c2p0g    = (float*)(ws + POSF);
  float* c2p1023g = c2p0g + 49152;
  float* p2c0g    = c2p0g + 98304;
  float* p2c1023g = c2p0g + 147456;

  prep_kernel<<<2255, 256, 0, stream>>>(Hx, pos, Wq, Wk, Wv, Wpk, Wpq,
                                        bq, bk, bv, bpk, bpq, whi, wlo, wall, ball);
  proj_gemm<<<2688, 256, 0, stream>>>(whi, wlo, wall, ball, ws);
  pos_dots<<<384, 256, 0, stream>>>(ws, c2p0g, c2p1023g, p2c0g, p2c1023g);
  attn_kernel<<<768, 128, 0, stream>>>(ws, (float*)d_out);
}

// Round 4
// 334.434 us; speedup vs baseline: 1.6545x; 1.0331x over previous
//
#include <hip/hip_runtime.h>
#include <math.h>

// DeBERTa disentangled self-attention, fused (MI355X / gfx950).
// B=2, S=2048, D=64, H=12, K_SPAN=512.
// score[i,j] = (q_i.k_j + q_i.pk[c] + k_j.pq[c]) / sqrt(192), c = clip(i-j+512,0,1023)
//
// prep:      fp32 -> bf16 hi/lo split of H|pos, bf16 W, biases (scratch in d_out head).
// proj_gemm: MFMA 16x16x32, X = hi+lo two-term product -> q/k/vT/pk/pq bf16 in ws.
// pos_dots:  c2p0/1023[bh][i] = q.pk[0/1023];  p2c0/1023[bh][j] = k.pq[0/1023].
// attn:      1-wave blocks (64 thr), grid 1536 = 8 XCD-groups x (3 bh x 64 itiles).
//            XCD swizzle keeps each XCD's K/V/pk/pq (~2.3MB) L2-resident.
//            Swapped-operand 32x32x16 flash attention; private LDS tables
//            (c2p [96 rel][32 i] natural conflict-free; p2c [64 j][128 rel] XOR);
//            fully-clamped jt fast path via pos_dots vectors; V loads hoisted.

#define S_LEN 2048
#define NH    12
#define TWOK  1024
#define QSZ   3145728   // 24 * 2048 * 64
#define PSZ   786432    // 12 * 1024 * 64
#define POSF  11010048  // 3*QSZ + 2*PSZ (u16 elements)

typedef __bf16 bf16x8 __attribute__((ext_vector_type(8)));
typedef unsigned short u16x8 __attribute__((ext_vector_type(8)));
typedef float f32x4  __attribute__((ext_vector_type(4)));
typedef float f32x16 __attribute__((ext_vector_type(16)));
typedef unsigned int u32x2 __attribute__((ext_vector_type(2)));
typedef unsigned int u32x4 __attribute__((ext_vector_type(4)));

__device__ __forceinline__ unsigned short f2bf(float f) {
  return __builtin_bit_cast(unsigned short, (__bf16)f);
}
__device__ __forceinline__ unsigned pk2bf(float a, float b) {
  return ((unsigned)__builtin_bit_cast(unsigned short, (__bf16)b) << 16)
       | (unsigned)__builtin_bit_cast(unsigned short, (__bf16)a);
}
__device__ __forceinline__ float bf2f(unsigned short h) {
  return __builtin_bit_cast(float, ((unsigned)h) << 16);
}
__device__ __forceinline__ bf16x8 ld_bf8(const unsigned short* p) {
  return __builtin_bit_cast(bf16x8, *(const u16x8*)p);
}

// ---------------------------------------------------------------- prep
__global__ __launch_bounds__(256) void prep_kernel(
    const float* __restrict__ Hx, const float* __restrict__ pos,
    const float* __restrict__ Wq, const float* __restrict__ Wk,
    const float* __restrict__ Wv, const float* __restrict__ Wpk,
    const float* __restrict__ Wpq,
    const float* __restrict__ bq, const float* __restrict__ bk,
    const float* __restrict__ bv, const float* __restrict__ bpk,
    const float* __restrict__ bpq,
    unsigned short* __restrict__ whi, unsigned short* __restrict__ wlo,
    unsigned short* __restrict__ wall, float* __restrict__ ball) {
  int idx = blockIdx.x * 256 + threadIdx.x;
  if (idx < 327680) {                       // H (4096x64) then pos (1024x64): hi/lo split
    float v = (idx < 262144) ? Hx[idx] : pos[idx - 262144];
    __bf16 hi = (__bf16)v;
    float lo = v - (float)hi;
    whi[idx] = __builtin_bit_cast(unsigned short, hi);
    wlo[idx] = f2bf(lo);
  } else if (idx < 573440) {                // W: q,k,v,pk,pq -> bf16, 3840x64
    int k = idx - 327680;
    int mat = k / 49152, off = k - mat * 49152;
    const float* W = mat==0?Wq: mat==1?Wk: mat==2?Wv: mat==3?Wpk:Wpq;
    wall[k] = f2bf(W[off]);
  } else if (idx < 577280) {                // biases, 3840
    int k = idx - 573440;
    int mat = k / 768, off = k - mat * 768;
    const float* B = mat==0?bq: mat==1?bk: mat==2?bv: mat==3?bpk:bpq;
    ball[k] = B[off];
  }
}

// ---------------------------------------------------------------- projection GEMM
__global__ __launch_bounds__(256) void proj_gemm(
    const unsigned short* __restrict__ whi, const unsigned short* __restrict__ wlo,
    const unsigned short* __restrict__ wall, const float* __restrict__ ball,
    unsigned short* __restrict__ ws) {
  unsigned short* qg  = ws;
  unsigned short* kg  = ws + QSZ;
  unsigned short* vtg = ws + 2 * QSZ;
  unsigned short* pkg = ws + 3 * QSZ;
  unsigned short* pqg = ws + 3 * QSZ + PSZ;

  int bid = blockIdx.x;
  int rbase, obase, wrow, isA;
  if (bid < 2304) { rbase = (bid / 36) * 64;        obase = (bid % 36) * 64; wrow = obase;        isA = 1; }
  else { int b2 = bid - 2304; rbase = 4096 + (b2 / 24) * 64; obase = (b2 % 24) * 64; wrow = 2304 + obase; isA = 0; }

  int tid = threadIdx.x, w = tid >> 6, l = tid & 63, lg = l >> 4, lr = l & 15;
  int xrow = rbase + w * 16 + lr;

  bf16x8 ah[2], al[2];
  #pragma unroll
  for (int ks = 0; ks < 2; ++ks) {
    ah[ks] = ld_bf8(whi + xrow * 64 + ks * 32 + 8 * lg);
    al[ks] = ld_bf8(wlo + xrow * 64 + ks * 32 + 8 * lg);
  }

  int mat = obase / 768;
  int h = ((obase % 768) >> 6);   // uniform per block

  #pragma unroll
  for (int jb = 0; jb < 4; ++jb) {
    f32x4 acc = {0.f, 0.f, 0.f, 0.f};
    #pragma unroll
    for (int ks = 0; ks < 2; ++ks) {
      bf16x8 bfrag = ld_bf8(wall + (wrow + jb * 16 + lr) * 64 + ks * 32 + 8 * lg);
      acc = __builtin_amdgcn_mfma_f32_16x16x32_bf16(ah[ks], bfrag, acc, 0, 0, 0);
      acc = __builtin_amdgcn_mfma_f32_16x16x32_bf16(al[ks], bfrag, acc, 0, 0, 0);
    }
    float bias = ball[wrow + jb * 16 + lr];
    int d = jb * 16 + lr;
    #pragma unroll
    for (int r = 0; r < 4; ++r) {
      int orow = rbase + w * 16 + 4 * lg + r;
      unsigned short val = f2bf(acc[r] + bias);
      if (isA) {
        int bb = orow >> 11, i = orow & 2047, bh = bb * NH + h;
        if (mat == 0)      qg[(bh * S_LEN + i) * 64 + d] = val;
        else if (mat == 1) kg[(bh * S_LEN + i) * 64 + d] = val;
        else               vtg[(bh * 64 + d) * S_LEN + i] = val;  // V transposed
      } else {
        int prow = orow - 4096;
        if (mat == 0) pkg[(h * TWOK + prow) * 64 + d] = val;
        else          pqg[(h * TWOK + prow) * 64 + d] = val;
      }
    }
  }
}

// ---------------------------------------------------------------- pos_dots
// c2p0/1023[bh*2048+i] = q_i . pk[0/1023];  p2c0/1023[bh*2048+j] = k_j . pq[0/1023]
__global__ __launch_bounds__(256) void pos_dots(
    const unsigned short* __restrict__ ws, float* __restrict__ c2p0,
    float* __restrict__ c2p1023, float* __restrict__ p2c0,
    float* __restrict__ p2c1023) {
  int t = blockIdx.x * 256 + threadIdx.x;     // [0, 98304)
  int isK = t >= 49152;
  int row = isK ? t - 49152 : t;              // bh*2048 + i
  int h = (row >> 11) % NH;
  const unsigned short* src = ws + (isK ? QSZ : 0) + row * 64;
  const unsigned short* pA = ws + 3 * QSZ + (isK ? PSZ : 0) + (h * TWOK) * 64;
  const unsigned short* pB = pA + 1023 * 64;
  float a0 = 0.f, a1 = 0.f;
  #pragma unroll
  for (int c = 0; c < 8; ++c) {
    u16x8 xv = *(const u16x8*)(src + c * 8);
    u16x8 av = *(const u16x8*)(pA + c * 8);
    u16x8 bv = *(const u16x8*)(pB + c * 8);
    #pragma unroll
    for (int e = 0; e < 8; ++e) {
      float x = bf2f(xv[e]);
      a0 += x * bf2f(av[e]);
      a1 += x * bf2f(bv[e]);
    }
  }
  if (isK) { p2c0[row] = a0; p2c1023[row] = a1; }
  else     { c2p0[row] = a0; c2p1023[row] = a1; }
}

// ---------------------------------------------------------------- fused attention
// 64 thr = 1 wave per block; grid 1536. bid -> (xcd g, bh, it32) so each XCD
// owns 3 bh (K/V/pk/pq L2-resident). LDS 22.5KB -> 7 blocks/CU.
__global__ __launch_bounds__(64, 2) void attn_kernel(
    const unsigned short* __restrict__ ws, float* __restrict__ out) {
  const unsigned short* qg  = ws;
  const unsigned short* kg  = ws + QSZ;
  const unsigned short* vtg = ws + 2 * QSZ;
  const unsigned short* pkg = ws + 3 * QSZ;
  const unsigned short* pqg = ws + 3 * QSZ + PSZ;
  const float* c2p0g    = (const float*)(ws + POSF);
  const float* c2p1023g = c2p0g + 49152;
  const float* p2c0g    = c2p0g + 98304;
  const float* p2c1023g = c2p0g + 147456;

  __shared__ __align__(16) unsigned short tblC[96 * 32];    // [rel][i]  6KB
  __shared__ __align__(16) unsigned short tblP[64 * 128];   // [j][rel] 16KB

  const int bid = blockIdx.x;
  const int g = bid & 7, r = bid >> 3;          // g ~ XCD (round-robin dispatch)
  const int bh = 8 * (r % 3) + g;               // XCD g owns bh {g, g+8, g+16}
  const int it32 = r / 3;                       // 0..63, 32 q-rows each
  const int b = bh / NH, h = bh - b * NH;
  const int l = threadIdx.x & 63;
  const int iL = l & 31, h5 = l >> 5;
  const int i0w = it32 * 32;
  const int ig = i0w + iL;

  const unsigned short* qb  = qg  + bh * (S_LEN * 64);
  const unsigned short* kb  = kg  + bh * (S_LEN * 64);
  const unsigned short* vb  = vtg + bh * (64 * S_LEN);
  const unsigned short* pkb = pkg + h * (TWOK * 64);
  const unsigned short* pqb = pqg + h * (TWOK * 64);

  const float CS = 1.4426950408889634f / sqrtf(192.0f);  // log2(e)/sqrt(3*64)

  // Q as B-frag: lane holds Q[col=i=iL][k = kc*16 + 8*h5 + e]
  bf16x8 qf[4];
  #pragma unroll
  for (int kc = 0; kc < 4; ++kc)
    qf[kc] = ld_bf8(qb + ig * 64 + kc * 16 + 8 * h5);

  const float c2pLO = c2p0g[bh * S_LEN + ig];
  const float c2pHI = c2p1023g[bh * S_LEN + ig];

  f32x16 ctx0 = 0.f, ctx1 = 0.f;
  float m_ = -1e30f, l_ = 0.f;

  char* tPw = (char*)tblP;
  char* pb0 = tPw + iL * 256;                  // own p2c rows (j=iL, 32+iL)
  char* pb1 = tPw + (32 + iL) * 256;
  const int wxor = (iL & 15) << 4;             // p2c write xor (row-based)

  for (int jt = 0; jt < 32; ++jt) {
    const int j0 = jt * 64;
    const int rlo = 512 + i0w - j0 - 63;   // unclipped min rel over wave tile
    const int rhi = rlo + 94;              // unclipped max

    // K as A-frag (rows j) - also reused as B-frag (cols j) for p2c bands
    bf16x8 kf0[4], kf1[4];
    #pragma unroll
    for (int kc = 0; kc < 4; ++kc) {
      kf0[kc] = ld_bf8(kb + (j0 + iL) * 64 + kc * 16 + 8 * h5);
      kf1[kc] = ld_bf8(kb + (j0 + 32 + iL) * 64 + kc * 16 + 8 * h5);
    }
    // V^T frags hoisted: latency hides under bands + softmax
    bf16x8 vf0[4], vf1[4];
    #pragma unroll
    for (int kc = 0; kc < 4; ++kc) {
      vf0[kc] = ld_bf8(vb + (iL) * S_LEN + j0 + kc * 16 + 8 * h5);
      vf1[kc] = ld_bf8(vb + (32 + iL) * S_LEN + j0 + kc * 16 + 8 * h5);
    }

    // QK^T swapped: D[row=j][col=i]; lane: i=iL, j = 32*js + (r&3)+8*(r>>2)+4*h5
    f32x16 s0 = 0.f, s1 = 0.f;
    #pragma unroll
    for (int kc = 0; kc < 4; ++kc) {
      s0 = __builtin_amdgcn_mfma_f32_32x32x16_bf16(kf0[kc], qf[kc], s0, 0, 0, 0);
      s1 = __builtin_amdgcn_mfma_f32_32x32x16_bf16(kf1[kc], qf[kc], s1, 0, 0, 0);
    }

    if (rlo >= 1023) {
      // -------- fully clamped high: add = c2p1023[i] + p2c1023[j]
      float pa = p2c1023g[bh * S_LEN + j0 + iL];
      float pb = p2c1023g[bh * S_LEN + j0 + 32 + iL];
      #pragma unroll
      for (int r = 0; r < 16; ++r) {
        const int j32 = (r & 3) + 8 * (r >> 2) + 4 * h5;
        s0[r] = (s0[r] + c2pHI + __shfl(pa, j32)) * CS;
        s1[r] = (s1[r] + c2pHI + __shfl(pb, j32)) * CS;
      }
    } else if (rhi <= 0) {
      // -------- fully clamped low: add = c2p0[i] + p2c0[j]
      float pa = p2c0g[bh * S_LEN + j0 + iL];
      float pb = p2c0g[bh * S_LEN + j0 + 32 + iL];
      #pragma unroll
      for (int r = 0; r < 16; ++r) {
        const int j32 = (r & 3) + 8 * (r >> 2) + 4 * h5;
        s0[r] = (s0[r] + c2pLO + __shfl(pa, j32)) * CS;
        s1[r] = (s1[r] + c2pLO + __shfl(pb, j32)) * CS;
      }
    } else {
      // -------- banded path
      const int rminc = rlo < 0 ? 0 : rlo;
      const int rmaxc = rhi > 1023 ? 1023 : rhi;
      const int bstart = rminc > 928 ? 928 : rminc;
      const int nbh = (rmaxc - bstart) >> 5;         // <= 2
      const int interior = (rlo >= 0) & (rhi <= 1023);
      int c_lo = (rminc - bstart) >> 5;
      int p0_lo, p1_hi;
      if (interior) {
        p0_lo = (rlo + 32 - bstart) >> 5;
        p1_hi = (rhi - 32 - bstart) >> 5;
      } else { p0_lo = c_lo; p1_hi = nbh; }

      // bands -> tables (prior gathers already consumed => LDS reuse safe)
      for (int nb = c_lo; nb <= nbh; ++nb) {
        const int rrow = bstart + nb * 32 + iL;
        const int doP0 = nb >= p0_lo, doP1 = nb <= p1_hi;
        f32x16 ac = 0.f, a0 = 0.f, a1 = 0.f;
        #pragma unroll
        for (int kc = 0; kc < 4; ++kc) {
          bf16x8 fk = ld_bf8(pkb + rrow * 64 + kc * 16 + 8 * h5);
          ac = __builtin_amdgcn_mfma_f32_32x32x16_bf16(fk, qf[kc], ac, 0, 0, 0);
        }
        if (doP0 | doP1) {
          #pragma unroll
          for (int kc = 0; kc < 4; ++kc) {
            bf16x8 fq = ld_bf8(pqb + rrow * 64 + kc * 16 + 8 * h5);
            if (doP0) a0 = __builtin_amdgcn_mfma_f32_32x32x16_bf16(fq, kf0[kc], a0, 0, 0, 0);
            if (doP1) a1 = __builtin_amdgcn_mfma_f32_32x32x16_bf16(fq, kf1[kc], a1, 0, 0, 0);
          }
        }
        // c2p -> [rel][i] natural layout (conflict-free): lane owns col i=iL
        #pragma unroll
        for (int q4 = 0; q4 < 4; ++q4) {
          const int Rq = nb * 32 + 8 * q4 + 4 * h5;
          #pragma unroll
          for (int e = 0; e < 4; ++e)
            tblC[(Rq + e) * 32 + iL] = f2bf(ac[4 * q4 + e]);
        }
        // p2c -> [j][rel] XOR layout, packed b64 writes
        #pragma unroll
        for (int q4 = 0; q4 < 4; ++q4) {
          const int off = ((nb * 32 + 8 * q4 + 4 * h5) * 2) ^ wxor;
          if (doP0) {
            u32x2 v0; v0[0] = pk2bf(a0[4*q4+0], a0[4*q4+1]); v0[1] = pk2bf(a0[4*q4+2], a0[4*q4+3]);
            *(u32x2*)(pb0 + off) = v0;
          }
          if (doP1) {
            u32x2 v1; v1[0] = pk2bf(a1[4*q4+0], a1[4*q4+1]); v1[1] = pk2bf(a1[4*q4+2], a1[4*q4+3]);
            *(u32x2*)(pb1 + off) = v1;
          }
        }
      }
      asm volatile("s_waitcnt lgkmcnt(0)" ::: "memory");  // wave-local write->read

      const int D0 = ig + 512 - j0;
      if (interior) {
        // clamp-free gathers; rb = D0 - bstart - j
        const int rb0 = D0 - bstart;
        #pragma unroll
        for (int r = 0; r < 16; ++r) {
          const int j32 = (r & 3) + 8 * (r >> 2) + 4 * h5;
          const int pxr = (j32 & 15) << 4;
          const int o0 = (rb0 - j32) * 2, o1 = o0 - 64;
          float c0v = bf2f(tblC[(rb0 - j32) * 32 + iL]);
          float c1v = bf2f(tblC[(rb0 - 32 - j32) * 32 + iL]);
          float p0v = bf2f(*(const unsigned short*)(tPw + j32 * 256 + (o0 ^ pxr)));
          float p1v = bf2f(*(const unsigned short*)(tPw + (32 + j32) * 256 + (o1 ^ pxr)));
          s0[r] = (s0[r] + c0v + p0v) * CS;
          s1[r] = (s1[r] + c1v + p1v) * CS;
        }
      } else {
        #pragma unroll
        for (int r = 0; r < 16; ++r) {
          const int j32 = (r & 3) + 8 * (r >> 2) + 4 * h5;
          const int pxr = (j32 & 15) << 4;
          int rel0 = D0 - j32;       rel0 = rel0 < 0 ? 0 : (rel0 > 1023 ? 1023 : rel0);
          int rel1 = D0 - 32 - j32;  rel1 = rel1 < 0 ? 0 : (rel1 > 1023 ? 1023 : rel1);
          const int rb0 = rel0 - bstart, rb1 = rel1 - bstart;
          float c0v = bf2f(tblC[rb0 * 32 + iL]);
          float c1v = bf2f(tblC[rb1 * 32 + iL]);
          float p0v = bf2f(*(const unsigned short*)(tPw + j32 * 256 + ((rb0 * 2) ^ pxr)));
          float p1v = bf2f(*(const unsigned short*)(tPw + (32 + j32) * 256 + ((rb1 * 2) ^ pxr)));
          s0[r] = (s0[r] + c0v + p0v) * CS;
          s1[r] = (s1[r] + c1v + p1v) * CS;
        }
      }
    }

    // -------- online softmax (lane owns full row i)
    float vmax = s0[0];
    #pragma unroll
    for (int r = 1; r < 16; ++r) vmax = fmaxf(vmax, s0[r]);
    #pragma unroll
    for (int r = 0; r < 16; ++r) vmax = fmaxf(vmax, s1[r]);
    vmax = fmaxf(vmax, __shfl_xor(vmax, 32));
    float mx = fmaxf(m_, vmax);
    float fs = __builtin_amdgcn_exp2f(m_ - mx);
    m_ = mx;
    float sum = 0.f;
    #pragma unroll
    for (int r = 0; r < 16; ++r) { s0[r] = __builtin_amdgcn_exp2f(s0[r] - mx); sum += s0[r]; }
    #pragma unroll
    for (int r = 0; r < 16; ++r) { s1[r] = __builtin_amdgcn_exp2f(s1[r] - mx); sum += s1[r]; }
    sum += __shfl_xor(sum, 32);
    l_ = l_ * fs + sum;
    if (!__all(fs == 1.0f)) { ctx0 *= fs; ctx1 *= fs; }   // defer-rescale (exact)

    // -------- repack P -> B-frags: cvt-pack + cross-half shfl + select
    bf16x8 pf[4];
    #pragma unroll
    for (int kc = 0; kc < 4; ++kc) {
      const int c = kc & 1;
      const f32x16& sj = (kc >> 1) ? s1 : s0;
      unsigned X0 = pk2bf(sj[8*c+0], sj[8*c+1]);
      unsigned X1 = pk2bf(sj[8*c+2], sj[8*c+3]);
      unsigned Y0 = pk2bf(sj[8*c+4], sj[8*c+5]);
      unsigned Y1 = pk2bf(sj[8*c+6], sj[8*c+7]);
      unsigned sx0 = (unsigned)__shfl_xor((int)X0, 32);
      unsigned sx1 = (unsigned)__shfl_xor((int)X1, 32);
      unsigned sy0 = (unsigned)__shfl_xor((int)Y0, 32);
      unsigned sy1 = (unsigned)__shfl_xor((int)Y1, 32);
      u32x4 f;
      f[0] = h5 ? sy0 : X0;
      f[1] = h5 ? sy1 : X1;
      f[2] = h5 ? Y0 : sx0;
      f[3] = h5 ? Y1 : sx1;
      pf[kc] = __builtin_bit_cast(bf16x8, f);
    }

    // -------- PV: ctx = mfma(V^T, P) -> D[row=d][col=i]; lane owns ctx row i
    #pragma unroll
    for (int kc = 0; kc < 4; ++kc) {
      ctx0 = __builtin_amdgcn_mfma_f32_32x32x16_bf16(vf0[kc], pf[kc], ctx0, 0, 0, 0);
      ctx1 = __builtin_amdgcn_mfma_f32_32x32x16_bf16(vf1[kc], pf[kc], ctx1, 0, 0, 0);
    }
  }

  // -------- epilogue: lane owns row i = ig -> float4 stores
  float inv = 1.0f / l_;
  float* ob = out + (b * S_LEN + ig) * 768 + h * 64;
  #pragma unroll
  for (int q4 = 0; q4 < 4; ++q4) {
    float4 o0 = {ctx0[4*q4+0]*inv, ctx0[4*q4+1]*inv, ctx0[4*q4+2]*inv, ctx0[4*q4+3]*inv};
    *(float4*)(ob + 8 * q4 + 4 * h5) = o0;
    float4 o1 = {ctx1[4*q4+0]*inv, ctx1[4*q4+1]*inv, ctx1[4*q4+2]*inv, ctx1[4*q4+3]*inv};
    *(float4*)(ob + 32 + 8 * q4 + 4 * h5) = o1;
  }
}

extern "C" void kernel_launch(void* const* d_in, const int* in_sizes, int n_in,
                              void* d_out, int out_size, void* d_ws, size_t ws_size,
                              hipStream_t stream) {
  (void)in_sizes; (void)n_in; (void)out_size; (void)ws_size;
  const float* Hx  = (const float*)d_in[0];
  const float* pos = (const float*)d_in[1];
  // d_in[2] = relative_pos: deterministic (i-j), recomputed inline -> unused
  const float* Wq  = (const float*)d_in[3];  const float* bq  = (const float*)d_in[4];
  const float* Wk  = (const float*)d_in[5];  const float* bk  = (const float*)d_in[6];
  const float* Wv  = (const float*)d_in[7];  const float* bv  = (const float*)d_in[8];
  const float* Wpq = (const float*)d_in[9];  const float* bpq = (const float*)d_in[10];
  const float* Wpk = (const float*)d_in[11]; const float* bpk = (const float*)d_in[12];
  unsigned short* ws = (unsigned short*)d_ws;

  // prep scratch lives in d_out's head (attn rewrites all of d_out later)
  unsigned short* scratch = (unsigned short*)d_out;
  unsigned short* whi  = scratch;            // 327680 u16
  unsigned short* wlo  = scratch + 327680;   // 327680 u16
  unsigned short* wall = scratch + 655360;   // 245760 u16
  float*          ball = (float*)(scratch + 901120);  // 3840 f32

  float* c2p0g    = (float*)(ws + POSF);
  float* c2p1023g = c2p0g + 49152;
  float* p2c0g    = c2p0g + 98304;
  float* p2c1023g = c2p0g + 147456;

  prep_kernel<<<2255, 256, 0, stream>>>(Hx, pos, Wq, Wk, Wv, Wpk, Wpq,
                                        bq, bk, bv, bpk, bpq, whi, wlo, wall, ball);
  proj_gemm<<<2688, 256, 0, stream>>>(whi, wlo, wall, ball, ws);
  pos_dots<<<384, 256, 0, stream>>>(ws, c2p0g, c2p1023g, p2c0g, p2c1023g);
  attn_kernel<<<1536, 64, 0, stream>>>(ws, (float*)d_out);
}